// Round 12
// baseline (248.402 us; speedup 1.0000x reference)
//
#include <hip/hip_runtime.h>

typedef _Float16 f16;
typedef _Float16 f16x8 __attribute__((ext_vector_type(8)));
typedef _Float16 f16x4 __attribute__((ext_vector_type(4)));
typedef float f32x4 __attribute__((ext_vector_type(4)));

#define B 16
#define C 256
#define H 32
#define W 32
#define HW (H * W)
#define T_STEPS 8
#define EPS_GN 1e-5f
#define EPS_NORM 1e-12f
#define N_ELEM ((size_t)B * C * HW)

// ---------------- GroupNorm(c)*gn_w + gn_b + conv_b -> ch3 (f32, blocked), + es zero
// ch3 layout: [b][row 32][cog 64][col 32][4]  (f32)
__global__ __launch_bounds__(256) void gn_kernel(
    const float* __restrict__ c, const float* __restrict__ gn_w,
    const float* __restrict__ gn_b, const float* __restrict__ conv_b,
    float* __restrict__ ch3, float* __restrict__ es) {
    int blk = blockIdx.x;          // b*64 + g
    int b = blk >> 6, g = blk & 63;
    if (blk == 0 && threadIdx.x < (T_STEPS + 1) * B) es[threadIdx.x] = 0.0f;
    const float* src = c + ((size_t)(b * C + 4 * g)) * HW;
    float sum = 0.f, sq = 0.f;
    for (int i = threadIdx.x; i < 4 * HW; i += 256) {
        float v = src[i];
        sum += v; sq += v * v;
    }
    #pragma unroll
    for (int o = 32; o > 0; o >>= 1) {
        sum += __shfl_down(sum, o, 64);
        sq  += __shfl_down(sq, o, 64);
    }
    __shared__ float s1[4], s2[4];
    if ((threadIdx.x & 63) == 0) { s1[threadIdx.x >> 6] = sum; s2[threadIdx.x >> 6] = sq; }
    __syncthreads();
    sum = s1[0] + s1[1] + s1[2] + s1[3];
    sq  = s2[0] + s2[1] + s2[2] + s2[3];
    float mean = sum * (1.0f / (4 * HW));
    float var  = sq  * (1.0f / (4 * HW)) - mean * mean;
    float scale = rsqrtf(var + EPS_GN);
    float wk[4], bk[4];
    #pragma unroll
    for (int k = 0; k < 4; k++) {
        wk[k] = gn_w[4 * g + k] * scale;
        bk[k] = gn_b[4 * g + k] + conv_b[4 * g + k];
    }
    for (int pix = threadIdx.x; pix < HW; pix += 256) {
        int row = pix >> 5, col = pix & 31;
        f32x4 o;
        #pragma unroll
        for (int k = 0; k < 4; k++)
            o[k] = (src[k * HW + pix] - mean) * wk[k] + bk[k];
        *reinterpret_cast<f32x4*>(
            ch3 + (((size_t)((b * 32 + row) * 64 + g)) * 32 + col) * 4) = o;
    }
}

// ---------------- initial x normalize: f32 x0 (NCHW) + f16 (blocked NHWC) --
// xh layout: [b][row 32][oct 32][col 32][8]  (f16)
__global__ __launch_bounds__(256) void normx_kernel(
    const float* __restrict__ x, float* __restrict__ x0, f16* __restrict__ xh) {
    int gid = blockIdx.x * 256 + threadIdx.x;   // (b, g, pix)
    int b = gid >> 16;
    int rem = gid & 65535;
    int g = rem >> 10, pix = rem & 1023;
    int row = pix >> 5, col = pix & 31;
    size_t base = ((size_t)(b * C + 4 * g)) * HW + pix;
    float v0 = x[base], v1 = x[base + HW], v2 = x[base + 2 * HW], v3 = x[base + 3 * HW];
    float nrm = sqrtf(v0 * v0 + v1 * v1 + v2 * v2 + v3 * v3);
    float inv = 1.0f / fmaxf(nrm, EPS_NORM);
    v0 *= inv; v1 *= inv; v2 *= inv; v3 *= inv;
    x0[base] = v0; x0[base + HW] = v1; x0[base + 2 * HW] = v2; x0[base + 3 * HW] = v3;
    f16x4 hv = {(f16)v0, (f16)v1, (f16)v2, (f16)v3};
    *reinterpret_cast<f16x4*>(
        xh + ((((size_t)(b * 32 + row)) * 32 + (g >> 1)) * 32 + col) * 8 + (g & 1) * 4) = hv;
}

// ------- weight permute: conv_w [co][ci][3][3] f32 -> wh2 [khkw][ci/8][co][8] f16
__global__ __launch_bounds__(256) void wconvert_kernel(
    const float* __restrict__ cw, f16* __restrict__ wh2) {
    int idx = blockIdx.x * 256 + threadIdx.x;   // k*2^16 | oct*2^11 | co*2^3 | j
    int j   = idx & 7;
    int co  = (idx >> 3) & 255;
    int oct = (idx >> 11) & 31;
    int k   = idx >> 16;
    int ci  = oct * 8 + j;
    wh2[idx] = (f16)cw[((size_t)(co * C + ci)) * 9 + k];
}

// ---------------- fused MFMA conv + oscillator update ----------------------
// r7 structure: 512 blocks, 4 waves, 2 blocks/CU. Block = (b, 64co, 4r x 32c).
// Wave (ph, khf). Barrier-free flat K-loop (36 iters unrolled), af ring
// prefetch DEPTH-3, setprio around MFMA cluster, private per-wave LDS X tile,
// W direct from global (L2-resident). Epilogue unchanged from r10.
__global__ __launch_bounds__(256, 2) void conv_update_kernel(
    const f16* __restrict__ xh, const f16* __restrict__ wh2,
    const float* __restrict__ ch3, const float* __restrict__ xs_prev,
    const float* __restrict__ omg, const float* __restrict__ gamma_p,
    float* __restrict__ xs_out, f16* __restrict__ xh_out,
    float* __restrict__ es_b, int write_xh) {
    __shared__ __align__(16) char lds[49152];
    __shared__ float red[4];
    auto Xs = reinterpret_cast<f16 (*)[4][4][35][8]>(lds);  // [wv][oct][row][col][8ci]
    float* xpf = reinterpret_cast<float*>(lds);             // [64co][128pix] f32 (epilogue)
    f16*   fh  = reinterpret_cast<f16*>(lds + 32768);       // [8oct][4row][32col][8] f16

    const int bid  = blockIdx.x;
    const int pixt = bid & 7;
    const int cot  = (bid >> 3) & 3;
    const int b    = bid >> 5;
    const int co0  = cot * 64;
    const int tid  = threadIdx.x;
    const int lane = tid & 63;
    const int wv   = tid >> 6;
    const int n16  = lane & 15;
    const int grp  = lane >> 4;
    const int ph   = wv & 1;
    const int khf  = wv >> 1;
    const int r0   = pixt * 4 + 2 * ph;   // first interior image row

    // zero halo cols (0, 33, 34) of this wave's region + OOB halo rows
    {
        f16x8 z = {};
        for (int u = lane; u < 48; u += 64) {
            int cc = u % 3, rr = (u / 3) & 3, oct = u / 12;
            int col = (cc == 0) ? 0 : (32 + cc);
            *reinterpret_cast<f16x8*>(&Xs[wv][oct][rr][col][0]) = z;
        }
        if (r0 - 1 < 0 || r0 + 2 > 31) {
            int rr = (r0 - 1 < 0) ? 0 : 3;
            for (int u = lane; u < 140; u += 64) {
                int col = u % 35, oct = u / 35;
                *reinterpret_cast<f16x8*>(&Xs[wv][oct][rr][col][0]) = z;
            }
        }
    }

    // staging unit map: 8 units/thread, unit u = lane + 64s
    int xcol[8], xoct[8], xrow[8];
    bool xok[8];
    #pragma unroll
    for (int s = 0; s < 8; s++) {
        int u = lane + 64 * s;
        xcol[s] = u & 31; xoct[s] = (u >> 5) & 3; xrow[s] = u >> 7;
        int ri = r0 - 1 + xrow[s];
        xok[s] = (ri >= 0 && ri < 32);
    }
    f16x8 xreg[8];

    auto LOAD_X = [&](int cchunk) {
        #pragma unroll
        for (int s = 0; s < 8; s++)
            if (xok[s])
                xreg[s] = *reinterpret_cast<const f16x8*>(
                    xh + ((((size_t)(b * 32 + r0 - 1 + xrow[s])) * 32
                           + cchunk * 4 + xoct[s]) * 32 + xcol[s]) * 8);
    };
    auto WRITE_X = [&]() {
        #pragma unroll
        for (int s = 0; s < 8; s++)
            if (xok[s])
                *reinterpret_cast<f16x8*>(&Xs[wv][xoct[s]][xrow[s]][xcol[s] + 1][0]) = xreg[s];
    };
    auto afload = [&](int khkw, int cchunk, f16x8* dst) {
        const f16* wp = wh2
            + ((size_t)((khkw * 32 + cchunk * 4 + grp) * 256) + co0 + n16) * 8;
        #pragma unroll
        for (int mt = 0; mt < 4; mt++)
            dst[mt] = *reinterpret_cast<const f16x8*>(wp + (size_t)mt * 16 * 8);
    };

    f32x4 acc[4][4];
    #pragma unroll
    for (int mt = 0; mt < 4; mt++)
        #pragma unroll
        for (int nt = 0; nt < 4; nt++) acc[mt][nt] = {0.f, 0.f, 0.f, 0.f};

    LOAD_X(khf * 4);
    WRITE_X();

    f16x8 afb[4][4];
    afload(0, khf * 4, afb[0]);
    afload(1, khf * 4, afb[1]);
    afload(2, khf * 4, afb[2]);

    // flat K-loop: n = i*9 + khkw, fully unrolled (all indices compile-time)
    #pragma unroll
    for (int n = 0; n < 36; n++) {
        const int i = n / 9, khkw = n % 9;
        if (khkw == 0 && i < 3) LOAD_X(khf * 4 + i + 1);   // T14: issue early
        if (n < 33) {                                       // af ring prefetch, depth 3
            const int m = n + 3;
            afload(m % 9, khf * 4 + m / 9, afb[m % 4]);
        }
        const int kh = khkw / 3, kw = khkw % 3;
        f16x8 bf[4];
        #pragma unroll
        for (int nt = 0; nt < 4; nt++)
            bf[nt] = *reinterpret_cast<const f16x8*>(
                &Xs[wv][grp][(nt >> 1) + kh][(nt & 1) * 16 + n16 + kw][0]);
        __builtin_amdgcn_s_setprio(1);
        #pragma unroll
        for (int mt = 0; mt < 4; mt++)
            #pragma unroll
            for (int nt = 0; nt < 4; nt++)
                acc[mt][nt] = __builtin_amdgcn_mfma_f32_16x16x32_f16(
                    afb[n % 4][mt], bf[nt], acc[mt][nt], 0, 0, 0);
        __builtin_amdgcn_s_setprio(0);
        if (khkw == 8 && i < 3) WRITE_X();
    }

    // chv (c_hat f32) loads issued before the exchange barriers
    const int clm0 = (khf * 2) * 16 + grp * 4;
    const int clm1 = (khf * 2 + 1) * 16 + grp * 4;
    f32x4 chv[2][4];
    #pragma unroll
    for (int m = 0; m < 2; m++) {
        const int cog = (co0 + (m ? clm1 : clm0)) >> 2;
        #pragma unroll
        for (int nt = 0; nt < 4; nt++) {
            const int rowl = 2 * ph + (nt >> 1);
            const int col  = (nt & 1) * 16 + n16;
            chv[m][nt] = *reinterpret_cast<const f32x4*>(
                ch3 + (((size_t)((b * 32 + pixt * 4 + rowl) * 64 + cog)) * 32 + col) * 4);
        }
    }

    // ---- normalize ownership: keep co-half (khf) in acc[0..1], send acc[2..3]
    if (khf) {
        #pragma unroll
        for (int nt = 0; nt < 4; nt++) {
            f32x4 t0 = acc[0][nt]; acc[0][nt] = acc[2][nt]; acc[2][nt] = t0;
            f32x4 t1 = acc[1][nt]; acc[1][nt] = acc[3][nt]; acc[3][nt] = t1;
        }
    }

    // ---------------- partial-acc exchange across K-halves ----------------
    float* exw = reinterpret_cast<float*>(lds + wv * 8960);
    #pragma unroll
    for (int m = 0; m < 2; m++)
        #pragma unroll
        for (int nt = 0; nt < 4; nt++)
            *reinterpret_cast<f32x4*>(exw + ((m * 4 + nt) * 64 + lane) * 4) = acc[2 + m][nt];
    __syncthreads();
    const float* exr = reinterpret_cast<const float*>(lds + (wv ^ 2) * 8960);
    #pragma unroll
    for (int m = 0; m < 2; m++)
        #pragma unroll
        for (int nt = 0; nt < 4; nt++) {
            f32x4 part = *reinterpret_cast<const f32x4*>(
                exr + ((m * 4 + nt) * 64 + lane) * 4);
            acc[m][nt] += part;
        }
    __syncthreads();   // exchange reads done; lds is reusable

    // ---------------- cooperative x_prev tile load (f32 NCHW, full lines) --
    #pragma unroll
    for (int s = 0; s < 8; s++) {
        int u = tid + 256 * s;
        int co = u >> 5, seg = u & 31;
        *reinterpret_cast<f32x4*>(xpf + co * 128 + seg * 4) =
            *reinterpret_cast<const f32x4*>(
                xs_prev + ((size_t)(b * C + co0 + co)) * HW + pixt * 128 + seg * 4);
    }
    __syncthreads();

    // ---------------- fused oscillator update (in-place in LDS) ----------
    const float gam = gamma_p[0];
    float e = 0.0f;
    #pragma unroll
    for (int m = 0; m < 2; m++) {
        const int cl = m ? clm1 : clm0;                // co - co0, %4 == 0
        const int co = co0 + cl;
        const float a0 = omg[co], a1 = omg[co + 1];
        const float a2 = omg[co + 2], a3 = omg[co + 3];
        const float o0 = sqrtf(a0 * a0 + a1 * a1);
        const float o1 = sqrtf(a2 * a2 + a3 * a3);
        #pragma unroll
        for (int nt = 0; nt < 4; nt++) {
            const int rowl = 2 * ph + (nt >> 1);
            const int col  = (nt & 1) * 16 + n16;
            const int pixl = rowl * 32 + col;
            float x0 = xpf[(cl + 0) * 128 + pixl];
            float x1 = xpf[(cl + 1) * 128 + pixl];
            float x2 = xpf[(cl + 2) * 128 + pixl];
            float x3 = xpf[(cl + 3) * 128 + pixl];
            float y0 = acc[m][nt][0] + chv[m][nt][0];
            float y1 = acc[m][nt][1] + chv[m][nt][1];
            float y2 = acc[m][nt][2] + chv[m][nt][2];
            float y3 = acc[m][nt][3] + chv[m][nt][3];
            float sv = x0 * y0 + x1 * y1 + x2 * y2 + x3 * y3;
            float d0 =  o0 * x1 + y0 - sv * x0;
            float d1 = -o0 * x0 + y1 - sv * x1;
            float d2 =  o1 * x3 + y2 - sv * x2;
            float d3 = -o1 * x2 + y3 - sv * x3;
            float n0 = x0 + gam * d0, n1 = x1 + gam * d1;
            float n2 = x2 + gam * d2, n3 = x3 + gam * d3;
            float nrm = sqrtf(n0 * n0 + n1 * n1 + n2 * n2 + n3 * n3);
            float inv = 1.0f / fmaxf(nrm, EPS_NORM);
            n0 *= inv; n1 *= inv; n2 *= inv; n3 *= inv;
            // in-place: this thread owns exactly these 4 (co,pix) slots
            xpf[(cl + 0) * 128 + pixl] = n0;
            xpf[(cl + 1) * 128 + pixl] = n1;
            xpf[(cl + 2) * 128 + pixl] = n2;
            xpf[(cl + 3) * 128 + pixl] = n3;
            f16x4 hx = {(f16)n0, (f16)n1, (f16)n2, (f16)n3};
            *reinterpret_cast<f16x4*>(
                fh + (((cl >> 3) * 4 + rowl) * 32 + col) * 8 + (cl & 4)) = hx;
            e -= sv;
        }
    }
    __syncthreads();

    // ---------------- cooperative full-line global writes ----------------
    #pragma unroll
    for (int s = 0; s < 8; s++) {
        int u = tid + 256 * s;
        int co = u >> 5, seg = u & 31;
        *reinterpret_cast<f32x4*>(
            xs_out + ((size_t)(b * C + co0 + co)) * HW + pixt * 128 + seg * 4) =
            *reinterpret_cast<const f32x4*>(xpf + co * 128 + seg * 4);
    }
    if (write_xh) {
        #pragma unroll
        for (int s = 0; s < 4; s++) {
            int u = tid + 256 * s;            // (oct, row, col) 16B units
            int col = u & 31, rowl = (u >> 5) & 3, oct = u >> 7;
            *reinterpret_cast<f16x8*>(
                xh_out + ((((size_t)(b * 32 + pixt * 4 + rowl)) * 32
                           + (co0 >> 3) + oct) * 32 + col) * 8) =
                *reinterpret_cast<const f16x8*>(fh + ((oct * 4 + rowl) * 32 + col) * 8);
        }
    }

    // ---------------- energy reduction ----------------
    #pragma unroll
    for (int o = 32; o > 0; o >>= 1) e += __shfl_down(e, o, 64);
    if (lane == 0) red[wv] = e;
    __syncthreads();
    if (tid == 0) atomicAdd(es_b + b, red[0] + red[1] + red[2] + red[3]);
}

extern "C" void kernel_launch(void* const* d_in, const int* in_sizes, int n_in,
                              void* d_out, int out_size, void* d_ws, size_t ws_size,
                              hipStream_t stream) {
    const float* x        = (const float*)d_in[0];
    const float* c        = (const float*)d_in[1];
    // d_in[2] = T (int scalar, known = 8)
    const float* gamma_p  = (const float*)d_in[3];
    const float* conv_w   = (const float*)d_in[4];
    const float* conv_b   = (const float*)d_in[5];
    const float* gn_w     = (const float*)d_in[6];
    const float* gn_b     = (const float*)d_in[7];
    const float* omg_par  = (const float*)d_in[8];

    float* out = (float*)d_out;
    float* es  = out + (size_t)T_STEPS * N_ELEM;   // (T+1, B) region

    // ws: ch3 f32 (16MB) | xh0 f16 (8MB) | xh1 f16 (8MB) | wh2 f16 (1.2MB)
    float* ch3 = (float*)d_ws;
    f16* xh0 = (f16*)(ch3 + N_ELEM);
    f16* xh1 = xh0 + N_ELEM;
    f16* wh2 = xh1 + N_ELEM;
    // f32 x0 (NCHW) borrows the xs[7] output slot (read only at t=0)
    float* x0f = out + (size_t)(T_STEPS - 1) * N_ELEM;

    gn_kernel<<<B * 64, 256, 0, stream>>>(c, gn_w, gn_b, conv_b, ch3, es);
    normx_kernel<<<(B * 64 * HW) / 256, 256, 0, stream>>>(x, x0f, xh0);
    wconvert_kernel<<<(9 * C * C) / 256, 256, 0, stream>>>(conv_w, wh2);

    f16* xh_bufs[2] = {xh0, xh1};
    const float* xp = x0f;
    for (int t = 0; t < T_STEPS; t++) {
        float* xs_t = out + (size_t)t * N_ELEM;
        conv_update_kernel<<<512, 256, 0, stream>>>(
            xh_bufs[t & 1], wh2, ch3, xp, omg_par, gamma_p,
            xs_t, xh_bufs[(t + 1) & 1], es + (size_t)(t + 1) * B,
            (t < T_STEPS - 1) ? 1 : 0);
        xp = xs_t;
    }
}

// Round 13
// 247.755 us; speedup vs baseline: 1.0026x; 1.0026x over previous
//
#include <hip/hip_runtime.h>

typedef _Float16 f16;
typedef _Float16 f16x8 __attribute__((ext_vector_type(8)));
typedef _Float16 f16x4 __attribute__((ext_vector_type(4)));
typedef float f32x4 __attribute__((ext_vector_type(4)));

#define B 16
#define C 256
#define H 32
#define W 32
#define HW (H * W)
#define T_STEPS 8
#define EPS_GN 1e-5f
#define EPS_NORM 1e-12f
#define N_ELEM ((size_t)B * C * HW)

// ---------------- GroupNorm(c)*gn_w + gn_b + conv_b -> ch3 (f32, blocked), + es zero
// ch3 layout: [b][row 32][cog 64][col 32][4]  (f32)
__global__ __launch_bounds__(256) void gn_kernel(
    const float* __restrict__ c, const float* __restrict__ gn_w,
    const float* __restrict__ gn_b, const float* __restrict__ conv_b,
    float* __restrict__ ch3, float* __restrict__ es) {
    int blk = blockIdx.x;          // b*64 + g
    int b = blk >> 6, g = blk & 63;
    if (blk == 0 && threadIdx.x < (T_STEPS + 1) * B) es[threadIdx.x] = 0.0f;
    const float* src = c + ((size_t)(b * C + 4 * g)) * HW;
    float sum = 0.f, sq = 0.f;
    for (int i = threadIdx.x; i < 4 * HW; i += 256) {
        float v = src[i];
        sum += v; sq += v * v;
    }
    #pragma unroll
    for (int o = 32; o > 0; o >>= 1) {
        sum += __shfl_down(sum, o, 64);
        sq  += __shfl_down(sq, o, 64);
    }
    __shared__ float s1[4], s2[4];
    if ((threadIdx.x & 63) == 0) { s1[threadIdx.x >> 6] = sum; s2[threadIdx.x >> 6] = sq; }
    __syncthreads();
    sum = s1[0] + s1[1] + s1[2] + s1[3];
    sq  = s2[0] + s2[1] + s2[2] + s2[3];
    float mean = sum * (1.0f / (4 * HW));
    float var  = sq  * (1.0f / (4 * HW)) - mean * mean;
    float scale = rsqrtf(var + EPS_GN);
    float wk[4], bk[4];
    #pragma unroll
    for (int k = 0; k < 4; k++) {
        wk[k] = gn_w[4 * g + k] * scale;
        bk[k] = gn_b[4 * g + k] + conv_b[4 * g + k];
    }
    for (int pix = threadIdx.x; pix < HW; pix += 256) {
        int row = pix >> 5, col = pix & 31;
        f32x4 o;
        #pragma unroll
        for (int k = 0; k < 4; k++)
            o[k] = (src[k * HW + pix] - mean) * wk[k] + bk[k];
        *reinterpret_cast<f32x4*>(
            ch3 + (((size_t)((b * 32 + row) * 64 + g)) * 32 + col) * 4) = o;
    }
}

// ---------------- initial x normalize: f32 x0 (NCHW) + f16 (blocked NHWC) --
// xh layout: [b][row 32][oct 32][col 32][8]  (f16)
__global__ __launch_bounds__(256) void normx_kernel(
    const float* __restrict__ x, float* __restrict__ x0, f16* __restrict__ xh) {
    int gid = blockIdx.x * 256 + threadIdx.x;   // (b, g, pix)
    int b = gid >> 16;
    int rem = gid & 65535;
    int g = rem >> 10, pix = rem & 1023;
    int row = pix >> 5, col = pix & 31;
    size_t base = ((size_t)(b * C + 4 * g)) * HW + pix;
    float v0 = x[base], v1 = x[base + HW], v2 = x[base + 2 * HW], v3 = x[base + 3 * HW];
    float nrm = sqrtf(v0 * v0 + v1 * v1 + v2 * v2 + v3 * v3);
    float inv = 1.0f / fmaxf(nrm, EPS_NORM);
    v0 *= inv; v1 *= inv; v2 *= inv; v3 *= inv;
    x0[base] = v0; x0[base + HW] = v1; x0[base + 2 * HW] = v2; x0[base + 3 * HW] = v3;
    f16x4 hv = {(f16)v0, (f16)v1, (f16)v2, (f16)v3};
    *reinterpret_cast<f16x4*>(
        xh + ((((size_t)(b * 32 + row)) * 32 + (g >> 1)) * 32 + col) * 8 + (g & 1) * 4) = hv;
}

// ------- weight permute: conv_w [co][ci][3][3] f32 -> wh2 [khkw][ci/8][co][8] f16
__global__ __launch_bounds__(256) void wconvert_kernel(
    const float* __restrict__ cw, f16* __restrict__ wh2) {
    int idx = blockIdx.x * 256 + threadIdx.x;   // k*2^16 | oct*2^11 | co*2^3 | j
    int j   = idx & 7;
    int co  = (idx >> 3) & 255;
    int oct = (idx >> 11) & 31;
    int k   = idx >> 16;
    int ci  = oct * 8 + j;
    wh2[idx] = (f16)cw[((size_t)(co * C + ci)) * 9 + k];
}

// ---------------- fused MFMA conv + oscillator update ----------------------
// r7 structure: 512 blocks, 4 waves, 2 blocks/CU. Block = (b, 64co, 4r x 32c).
// Wave (ph, khf). Barrier-free flat K-loop (36 iters unrolled), af ring
// prefetch DEPTH-3, setprio around MFMA cluster, private per-wave LDS X tile,
// W direct from global (L2-resident). Epilogue unchanged from r10.
__global__ __launch_bounds__(256, 2) void conv_update_kernel(
    const f16* __restrict__ xh, const f16* __restrict__ wh2,
    const float* __restrict__ ch3, const float* __restrict__ xs_prev,
    const float* __restrict__ omg, const float* __restrict__ gamma_p,
    float* __restrict__ xs_out, f16* __restrict__ xh_out,
    float* __restrict__ es_b, int write_xh) {
    __shared__ __align__(16) char lds[49152];
    __shared__ float red[4];
    auto Xs = reinterpret_cast<f16 (*)[4][4][35][8]>(lds);  // [wv][oct][row][col][8ci]
    float* xpf = reinterpret_cast<float*>(lds);             // [64co][128pix] f32 (epilogue)
    f16*   fh  = reinterpret_cast<f16*>(lds + 32768);       // [8oct][4row][32col][8] f16

    const int bid  = blockIdx.x;
    const int pixt = bid & 7;
    const int cot  = (bid >> 3) & 3;
    const int b    = bid >> 5;
    const int co0  = cot * 64;
    const int tid  = threadIdx.x;
    const int lane = tid & 63;
    const int wv   = tid >> 6;
    const int n16  = lane & 15;
    const int grp  = lane >> 4;
    const int ph   = wv & 1;
    const int khf  = wv >> 1;
    const int r0   = pixt * 4 + 2 * ph;   // first interior image row

    // zero halo cols (0, 33, 34) of this wave's region + OOB halo rows
    {
        f16x8 z = {};
        for (int u = lane; u < 48; u += 64) {
            int cc = u % 3, rr = (u / 3) & 3, oct = u / 12;
            int col = (cc == 0) ? 0 : (32 + cc);
            *reinterpret_cast<f16x8*>(&Xs[wv][oct][rr][col][0]) = z;
        }
        if (r0 - 1 < 0 || r0 + 2 > 31) {
            int rr = (r0 - 1 < 0) ? 0 : 3;
            for (int u = lane; u < 140; u += 64) {
                int col = u % 35, oct = u / 35;
                *reinterpret_cast<f16x8*>(&Xs[wv][oct][rr][col][0]) = z;
            }
        }
    }

    // staging unit map: 8 units/thread, unit u = lane + 64s
    int xcol[8], xoct[8], xrow[8];
    bool xok[8];
    #pragma unroll
    for (int s = 0; s < 8; s++) {
        int u = lane + 64 * s;
        xcol[s] = u & 31; xoct[s] = (u >> 5) & 3; xrow[s] = u >> 7;
        int ri = r0 - 1 + xrow[s];
        xok[s] = (ri >= 0 && ri < 32);
    }
    f16x8 xreg[8];

    auto LOAD_X = [&](int cchunk) {
        #pragma unroll
        for (int s = 0; s < 8; s++)
            if (xok[s])
                xreg[s] = *reinterpret_cast<const f16x8*>(
                    xh + ((((size_t)(b * 32 + r0 - 1 + xrow[s])) * 32
                           + cchunk * 4 + xoct[s]) * 32 + xcol[s]) * 8);
    };
    auto WRITE_X = [&]() {
        #pragma unroll
        for (int s = 0; s < 8; s++)
            if (xok[s])
                *reinterpret_cast<f16x8*>(&Xs[wv][xoct[s]][xrow[s]][xcol[s] + 1][0]) = xreg[s];
    };
    auto afload = [&](int khkw, int cchunk, f16x8* dst) {
        const f16* wp = wh2
            + ((size_t)((khkw * 32 + cchunk * 4 + grp) * 256) + co0 + n16) * 8;
        #pragma unroll
        for (int mt = 0; mt < 4; mt++)
            dst[mt] = *reinterpret_cast<const f16x8*>(wp + (size_t)mt * 16 * 8);
    };

    f32x4 acc[4][4];
    #pragma unroll
    for (int mt = 0; mt < 4; mt++)
        #pragma unroll
        for (int nt = 0; nt < 4; nt++) acc[mt][nt] = {0.f, 0.f, 0.f, 0.f};

    LOAD_X(khf * 4);
    WRITE_X();

    f16x8 afb[4][4];
    afload(0, khf * 4, afb[0]);
    afload(1, khf * 4, afb[1]);
    afload(2, khf * 4, afb[2]);

    // flat K-loop: n = i*9 + khkw, fully unrolled (all indices compile-time)
    #pragma unroll
    for (int n = 0; n < 36; n++) {
        const int i = n / 9, khkw = n % 9;
        if (khkw == 0 && i < 3) LOAD_X(khf * 4 + i + 1);   // T14: issue early
        if (n < 33) {                                       // af ring prefetch, depth 3
            const int m = n + 3;
            afload(m % 9, khf * 4 + m / 9, afb[m % 4]);
        }
        const int kh = khkw / 3, kw = khkw % 3;
        f16x8 bf[4];
        #pragma unroll
        for (int nt = 0; nt < 4; nt++)
            bf[nt] = *reinterpret_cast<const f16x8*>(
                &Xs[wv][grp][(nt >> 1) + kh][(nt & 1) * 16 + n16 + kw][0]);
        __builtin_amdgcn_s_setprio(1);
        #pragma unroll
        for (int mt = 0; mt < 4; mt++)
            #pragma unroll
            for (int nt = 0; nt < 4; nt++)
                acc[mt][nt] = __builtin_amdgcn_mfma_f32_16x16x32_f16(
                    afb[n % 4][mt], bf[nt], acc[mt][nt], 0, 0, 0);
        __builtin_amdgcn_s_setprio(0);
        if (khkw == 8 && i < 3) WRITE_X();
    }

    // chv (c_hat f32) loads issued before the exchange barriers
    const int clm0 = (khf * 2) * 16 + grp * 4;
    const int clm1 = (khf * 2 + 1) * 16 + grp * 4;
    f32x4 chv[2][4];
    #pragma unroll
    for (int m = 0; m < 2; m++) {
        const int cog = (co0 + (m ? clm1 : clm0)) >> 2;
        #pragma unroll
        for (int nt = 0; nt < 4; nt++) {
            const int rowl = 2 * ph + (nt >> 1);
            const int col  = (nt & 1) * 16 + n16;
            chv[m][nt] = *reinterpret_cast<const f32x4*>(
                ch3 + (((size_t)((b * 32 + pixt * 4 + rowl) * 64 + cog)) * 32 + col) * 4);
        }
    }

    // ---- normalize ownership: keep co-half (khf) in acc[0..1], send acc[2..3]
    if (khf) {
        #pragma unroll
        for (int nt = 0; nt < 4; nt++) {
            f32x4 t0 = acc[0][nt]; acc[0][nt] = acc[2][nt]; acc[2][nt] = t0;
            f32x4 t1 = acc[1][nt]; acc[1][nt] = acc[3][nt]; acc[3][nt] = t1;
        }
    }

    // ---------------- partial-acc exchange across K-halves ----------------
    float* exw = reinterpret_cast<float*>(lds + wv * 8960);
    #pragma unroll
    for (int m = 0; m < 2; m++)
        #pragma unroll
        for (int nt = 0; nt < 4; nt++)
            *reinterpret_cast<f32x4*>(exw + ((m * 4 + nt) * 64 + lane) * 4) = acc[2 + m][nt];
    __syncthreads();
    const float* exr = reinterpret_cast<const float*>(lds + (wv ^ 2) * 8960);
    #pragma unroll
    for (int m = 0; m < 2; m++)
        #pragma unroll
        for (int nt = 0; nt < 4; nt++) {
            f32x4 part = *reinterpret_cast<const f32x4*>(
                exr + ((m * 4 + nt) * 64 + lane) * 4);
            acc[m][nt] += part;
        }
    __syncthreads();   // exchange reads done; lds is reusable

    // ---------------- cooperative x_prev tile load (f32 NCHW, full lines) --
    #pragma unroll
    for (int s = 0; s < 8; s++) {
        int u = tid + 256 * s;
        int co = u >> 5, seg = u & 31;
        *reinterpret_cast<f32x4*>(xpf + co * 128 + seg * 4) =
            *reinterpret_cast<const f32x4*>(
                xs_prev + ((size_t)(b * C + co0 + co)) * HW + pixt * 128 + seg * 4);
    }
    __syncthreads();

    // ---------------- fused oscillator update (in-place in LDS) ----------
    const float gam = gamma_p[0];
    float e = 0.0f;
    #pragma unroll
    for (int m = 0; m < 2; m++) {
        const int cl = m ? clm1 : clm0;                // co - co0, %4 == 0
        const int co = co0 + cl;
        const float a0 = omg[co], a1 = omg[co + 1];
        const float a2 = omg[co + 2], a3 = omg[co + 3];
        const float o0 = sqrtf(a0 * a0 + a1 * a1);
        const float o1 = sqrtf(a2 * a2 + a3 * a3);
        #pragma unroll
        for (int nt = 0; nt < 4; nt++) {
            const int rowl = 2 * ph + (nt >> 1);
            const int col  = (nt & 1) * 16 + n16;
            const int pixl = rowl * 32 + col;
            float x0 = xpf[(cl + 0) * 128 + pixl];
            float x1 = xpf[(cl + 1) * 128 + pixl];
            float x2 = xpf[(cl + 2) * 128 + pixl];
            float x3 = xpf[(cl + 3) * 128 + pixl];
            float y0 = acc[m][nt][0] + chv[m][nt][0];
            float y1 = acc[m][nt][1] + chv[m][nt][1];
            float y2 = acc[m][nt][2] + chv[m][nt][2];
            float y3 = acc[m][nt][3] + chv[m][nt][3];
            float sv = x0 * y0 + x1 * y1 + x2 * y2 + x3 * y3;
            float d0 =  o0 * x1 + y0 - sv * x0;
            float d1 = -o0 * x0 + y1 - sv * x1;
            float d2 =  o1 * x3 + y2 - sv * x2;
            float d3 = -o1 * x2 + y3 - sv * x3;
            float n0 = x0 + gam * d0, n1 = x1 + gam * d1;
            float n2 = x2 + gam * d2, n3 = x3 + gam * d3;
            float nrm = sqrtf(n0 * n0 + n1 * n1 + n2 * n2 + n3 * n3);
            float inv = 1.0f / fmaxf(nrm, EPS_NORM);
            n0 *= inv; n1 *= inv; n2 *= inv; n3 *= inv;
            // in-place: this thread owns exactly these 4 (co,pix) slots
            xpf[(cl + 0) * 128 + pixl] = n0;
            xpf[(cl + 1) * 128 + pixl] = n1;
            xpf[(cl + 2) * 128 + pixl] = n2;
            xpf[(cl + 3) * 128 + pixl] = n3;
            f16x4 hx = {(f16)n0, (f16)n1, (f16)n2, (f16)n3};
            *reinterpret_cast<f16x4*>(
                fh + (((cl >> 3) * 4 + rowl) * 32 + col) * 8 + (cl & 4)) = hx;
            e -= sv;
        }
    }
    __syncthreads();

    // ---------------- cooperative full-line global writes ----------------
    #pragma unroll
    for (int s = 0; s < 8; s++) {
        int u = tid + 256 * s;
        int co = u >> 5, seg = u & 31;
        *reinterpret_cast<f32x4*>(
            xs_out + ((size_t)(b * C + co0 + co)) * HW + pixt * 128 + seg * 4) =
            *reinterpret_cast<const f32x4*>(xpf + co * 128 + seg * 4);
    }
    if (write_xh) {
        #pragma unroll
        for (int s = 0; s < 4; s++) {
            int u = tid + 256 * s;            // (oct, row, col) 16B units
            int col = u & 31, rowl = (u >> 5) & 3, oct = u >> 7;
            *reinterpret_cast<f16x8*>(
                xh_out + ((((size_t)(b * 32 + pixt * 4 + rowl)) * 32
                           + (co0 >> 3) + oct) * 32 + col) * 8) =
                *reinterpret_cast<const f16x8*>(fh + ((oct * 4 + rowl) * 32 + col) * 8);
        }
    }

    // ---------------- energy reduction ----------------
    #pragma unroll
    for (int o = 32; o > 0; o >>= 1) e += __shfl_down(e, o, 64);
    if (lane == 0) red[wv] = e;
    __syncthreads();
    if (tid == 0) atomicAdd(es_b + b, red[0] + red[1] + red[2] + red[3]);
}

extern "C" void kernel_launch(void* const* d_in, const int* in_sizes, int n_in,
                              void* d_out, int out_size, void* d_ws, size_t ws_size,
                              hipStream_t stream) {
    const float* x        = (const float*)d_in[0];
    const float* c        = (const float*)d_in[1];
    // d_in[2] = T (int scalar, known = 8)
    const float* gamma_p  = (const float*)d_in[3];
    const float* conv_w   = (const float*)d_in[4];
    const float* conv_b   = (const float*)d_in[5];
    const float* gn_w     = (const float*)d_in[6];
    const float* gn_b     = (const float*)d_in[7];
    const float* omg_par  = (const float*)d_in[8];

    float* out = (float*)d_out;
    float* es  = out + (size_t)T_STEPS * N_ELEM;   // (T+1, B) region

    // ws: ch3 f32 (16MB) | xh0 f16 (8MB) | xh1 f16 (8MB) | wh2 f16 (1.2MB)
    float* ch3 = (float*)d_ws;
    f16* xh0 = (f16*)(ch3 + N_ELEM);
    f16* xh1 = xh0 + N_ELEM;
    f16* wh2 = xh1 + N_ELEM;
    // f32 x0 (NCHW) borrows the xs[7] output slot (read only at t=0)
    float* x0f = out + (size_t)(T_STEPS - 1) * N_ELEM;

    gn_kernel<<<B * 64, 256, 0, stream>>>(c, gn_w, gn_b, conv_b, ch3, es);
    normx_kernel<<<(B * 64 * HW) / 256, 256, 0, stream>>>(x, x0f, xh0);
    wconvert_kernel<<<(9 * C * C) / 256, 256, 0, stream>>>(conv_w, wh2);

    f16* xh_bufs[2] = {xh0, xh1};
    const float* xp = x0f;
    for (int t = 0; t < T_STEPS; t++) {
        float* xs_t = out + (size_t)t * N_ELEM;
        conv_update_kernel<<<512, 256, 0, stream>>>(
            xh_bufs[t & 1], wh2, ch3, xp, omg_par, gamma_p,
            xs_t, xh_bufs[(t + 1) & 1], es + (size_t)(t + 1) * B,
            (t < T_STEPS - 1) ? 1 : 0);
        xp = xs_t;
    }
}